// Round 17
// baseline (436.348 us; speedup 1.0000x reference)
//
#include <hip/hip_runtime.h>

// ICNN_net_1503238553972 — round 17: monolithic block = fhat(128 rows) then
// vnet-ILP2 (same 128 rows). Kills the combine kernel and the g_fh/g_grad
// global round-trip (~60 us of R11-16's constant overhead). fh crosses the
// phase boundary via a 1 KB wave-local LDS buffer; epilogue writes d_out
// directly. Grid 3907, LDS 50176 (H 32K + arenas 48K overlaid + FH 1K)
// -> 3 blocks/CU; phase mix across blocks restores fhat/vnet co-scheduling.

typedef _Float16 v2h __attribute__((ext_vector_type(2)));
typedef __fp16   v2hf __attribute__((ext_vector_type(2)));
typedef _Float16 v4h __attribute__((ext_vector_type(4)));
typedef _Float16 v8h __attribute__((ext_vector_type(8)));
typedef float    v4f __attribute__((ext_vector_type(4)));

__device__ __forceinline__ v2h cvt_pk(float a, float b){
  v2hf r = __builtin_amdgcn_cvt_pkrtz(a, b);
  union { v2hf f; v2h h; } u; u.f = r;
  return u.h;
}

#define NPTS 500000
#define NBLK ((NPTS + 127) / 128)   // 3907

// offsets in halves inside g_w16
#define OFF_FW    0               // f2..f5: L*16384, [o*128+k]
#define OFF_V2Z   65536           // [j*64+k]
#define OFF_V3Z   69632
#define OFF_V2ZT  73728           // [k*64+j]
#define OFF_V3ZT  77824
#define OFF_VL1T  81920           // [c*64+j]
#define OFF_V2XT  82048
#define OFF_V3XT  82176
#define OFF_VFZ   82304           // [64]
#define OFF_FFW   82368           // [c*128+k]
#define OFF_F1W   82624           // [oc*2+c]
#define W16_DATA  82880
#define W16_TOTAL (W16_DATA + 2048)   // zero pad: junk A-rows stay in-bounds

__device__ __align__(16) _Float16 g_w16[W16_TOTAL];

#if defined(__has_builtin)
#if __has_builtin(__builtin_amdgcn_fdot2)
#define FDOT2(a,b,c) __builtin_amdgcn_fdot2((a),(b),(c),false)
#endif
#endif
#ifndef FDOT2
__device__ __forceinline__ float fdot2_fb(v2h a, v2h b, float c){
  return fmaf((float)a.x, (float)b.x, fmaf((float)a.y, (float)b.y, c));
}
#define FDOT2(a,b,c) fdot2_fb((a),(b),(c))
#endif

__device__ __forceinline__ float srelu(float x){
  float c = fminf(fmaxf(x, 0.f), 1.f);
  return c * fmaf(-0.5f, c, x);
}
__device__ __forceinline__ float sreluD(float x){
  return fminf(fmaxf(x, 0.f), 1.f);
}
__device__ __forceinline__ float sreluD_from_z(float z){
  return fminf(sqrtf(2.f * z), 1.f);
}
__device__ __forceinline__ float dot8(v8h a, v8h b, float s){
  const v2h* ap = (const v2h*)&a;
  const v2h* bp = (const v2h*)&b;
  s = FDOT2(ap[0], bp[0], s);
  s = FDOT2(ap[1], bp[1], s);
  s = FDOT2(ap[2], bp[2], s);
  s = FDOT2(ap[3], bp[3], s);
  return s;
}

// ---- packed f16 activations (2 f32 in -> 2 f16 out) ----
__device__ __forceinline__ v2h lrelu_pk(float a, float b){
  v2h x = cvt_pk(a, b);
  v2h m = x * (v2h){(_Float16)0.01f, (_Float16)0.01f};
  return __builtin_elementwise_max(x, m);
}
__device__ __forceinline__ v2h srelu_pk(float a, float b){
  v2h x = cvt_pk(a, b);
  const v2h z0 = (v2h){(_Float16)0.f, (_Float16)0.f};
  const v2h o1 = (v2h){(_Float16)1.f, (_Float16)1.f};
  const v2h hf = (v2h){(_Float16)0.5f, (_Float16)0.5f};
  v2h c = __builtin_elementwise_min(__builtin_elementwise_max(x, z0), o1);
  v2h t = x - c * hf;
  return c * t;
}

// ---------------- prep: fp32 weights -> f16 layouts (+zero pad) ----------------
__global__ __launch_bounds__(256) void prep_kernel(
  const float* __restrict__ f2w, const float* __restrict__ f3w,
  const float* __restrict__ f4w, const float* __restrict__ f5w,
  const float* __restrict__ V2z, const float* __restrict__ V3z,
  const float* __restrict__ Vl1, const float* __restrict__ V2x,
  const float* __restrict__ V3x, const float* __restrict__ Vfz,
  const float* __restrict__ ffw, const float* __restrict__ f1w)
{
  const int i = blockIdx.x * 256 + threadIdx.x;
  if (i >= W16_TOTAL) return;
  if (i >= W16_DATA){ g_w16[i] = (_Float16)0.f; return; }
  float v;
  if (i < 65536){
    const float* W[4] = {f2w, f3w, f4w, f5w};
    v = W[i >> 14][i & 16383];
  } else if (i < 69632)  v = V2z[i - 65536];
  else if (i < 73728)    v = V3z[i - 69632];
  else if (i < 77824){ int r = i - 73728; v = V2z[(r & 63)*64 + (r >> 6)]; }
  else if (i < 81920){ int r = i - 77824; v = V3z[(r & 63)*64 + (r >> 6)]; }
  else if (i < 82048){ int r = i - 81920; v = Vl1[(r & 63)*2 + (r >> 6)]; }
  else if (i < 82176){ int r = i - 82048; v = V2x[(r & 63)*2 + (r >> 6)]; }
  else if (i < 82304){ int r = i - 82176; v = V3x[(r & 63)*2 + (r >> 6)]; }
  else if (i < 82368)    v = Vfz[i - 82304];
  else if (i < 82624)    v = ffw[i - 82368];
  else                   v = f1w[i - 82624];
  g_w16[i] = (_Float16)v;
}

// ================= fhat phase: 256 thr, 128 rows =================
__device__ __forceinline__ void fh_layer(_Float16* H,
    const _Float16* __restrict__ Wl, const float* __restrict__ Bp,
    int w, int lm, int q)
{
  v4f acc[2][8];
#pragma unroll
  for (int mt = 0; mt < 2; ++mt)
#pragma unroll
    for (int nt = 0; nt < 8; ++nt) acc[mt][nt] = (v4f){0.f,0.f,0.f,0.f};

#pragma unroll
  for (int kt = 0; kt < 4; ++kt){
    const int sw = ((kt*4 + q) ^ lm) << 3;
    v8h A0 = *(const v8h*)(Wl + (w*32      + lm)*128 + kt*32 + q*8);
    v8h A1 = *(const v8h*)(Wl + (w*32 + 16 + lm)*128 + kt*32 + q*8);
#pragma unroll
    for (int nt = 0; nt < 8; ++nt){
      v8h B = *(const v8h*)(H + (nt*16 + lm)*128 + sw);
      acc[0][nt] = __builtin_amdgcn_mfma_f32_16x16x32_f16(A0, B, acc[0][nt], 0,0,0);
      acc[1][nt] = __builtin_amdgcn_mfma_f32_16x16x32_f16(A1, B, acc[1][nt], 0,0,0);
    }
  }
  __syncthreads();   // all waves' B reads complete before any write
#pragma unroll
  for (int mt = 0; mt < 2; ++mt){
    const int o0 = w*32 + mt*16 + q*4;
    const v4f bv = *(const v4f*)(Bp + o0);
    const int coff = (((o0 >> 3) ^ lm) << 3) + (o0 & 7);
#pragma unroll
    for (int nt = 0; nt < 8; ++nt){
      v4h hv;
      *(v2h*)&hv       = lrelu_pk(acc[mt][nt][0] + bv[0], acc[mt][nt][1] + bv[1]);
      *((v2h*)&hv + 1) = lrelu_pk(acc[mt][nt][2] + bv[2], acc[mt][nt][3] + bv[3]);
      *(v4h*)(H + (nt*16 + lm)*128 + coff) = hv;
    }
  }
  __syncthreads();   // writes visible before next layer's reads
}

// ================= vnet phase: 2-pipeline wave-private bodies =================
__device__ __forceinline__ void vfwd2(const _Float16* zinA, _Float16* zoutA,
    const _Float16* zinB, _Float16* zoutB,
    const _Float16* __restrict__ Wz, const _Float16* __restrict__ WxT,
    float dA0, float dA1, float dB0, float dB1, int lm, int q)
{
  v4f accA[4], accB[4];
#pragma unroll
  for (int mt = 0; mt < 4; ++mt){
    accA[mt] = (v4f){0.f,0.f,0.f,0.f};
    accB[mt] = (v4f){0.f,0.f,0.f,0.f};
  }
  const int rs = lm & 7;
#pragma unroll
  for (int kt = 0; kt < 2; ++kt){
    const int sw = (((kt*4 + q) ^ rs) << 3);
    v8h BA = *(const v8h*)(zinA + lm*64 + sw);
    v8h BB = *(const v8h*)(zinB + lm*64 + sw);
#pragma unroll
    for (int mt = 0; mt < 4; ++mt){
      v8h A = *(const v8h*)(Wz + (mt*16 + lm)*64 + kt*32 + q*8);
      accA[mt] = __builtin_amdgcn_mfma_f32_16x16x32_f16(A, BA, accA[mt], 0,0,0);
      accB[mt] = __builtin_amdgcn_mfma_f32_16x16x32_f16(A, BB, accB[mt], 0,0,0);
    }
  }
#pragma unroll
  for (int mt = 0; mt < 4; ++mt){
    const int o0 = mt*16 + q*4;
    const int off = (((o0 >> 3) ^ rs) << 3) + (o0 & 7);
    float wx0[4], wx1[4];
#pragma unroll
    for (int reg = 0; reg < 4; ++reg){
      wx0[reg] = (float)WxT[o0 + reg];
      wx1[reg] = (float)WxT[64 + o0 + reg];
    }
    float vA[4], vB[4];
#pragma unroll
    for (int reg = 0; reg < 4; ++reg){
      vA[reg] = accA[mt][reg] + wx0[reg]*dA0 + wx1[reg]*dA1;
      vB[reg] = accB[mt][reg] + wx0[reg]*dB0 + wx1[reg]*dB1;
    }
    v4h hA, hB;
    *(v2h*)&hA       = srelu_pk(vA[0], vA[1]);
    *((v2h*)&hA + 1) = srelu_pk(vA[2], vA[3]);
    *(v2h*)&hB       = srelu_pk(vB[0], vB[1]);
    *((v2h*)&hB + 1) = srelu_pk(vB[2], vB[3]);
    *(v4h*)(zoutA + lm*64 + off) = hA;
    *(v4h*)(zoutB + lm*64 + off) = hB;
  }
}

__device__ __forceinline__ void vbwd2(const _Float16* ginA, _Float16* zioA,
    const _Float16* ginB, _Float16* zioB,
    const _Float16* __restrict__ WT, int lm, int q)
{
  v4f accA[4], accB[4];
#pragma unroll
  for (int mt = 0; mt < 4; ++mt){
    accA[mt] = (v4f){0.f,0.f,0.f,0.f};
    accB[mt] = (v4f){0.f,0.f,0.f,0.f};
  }
  const int rs = lm & 7;
#pragma unroll
  for (int kt = 0; kt < 2; ++kt){
    const int sw = (((kt*4 + q) ^ rs) << 3);
    v8h BA = *(const v8h*)(ginA + lm*64 + sw);
    v8h BB = *(const v8h*)(ginB + lm*64 + sw);
#pragma unroll
    for (int mt = 0; mt < 4; ++mt){
      v8h A = *(const v8h*)(WT + (mt*16 + lm)*64 + kt*32 + q*8);
      accA[mt] = __builtin_amdgcn_mfma_f32_16x16x32_f16(A, BA, accA[mt], 0,0,0);
      accB[mt] = __builtin_amdgcn_mfma_f32_16x16x32_f16(A, BB, accB[mt], 0,0,0);
    }
  }
#pragma unroll
  for (int mt = 0; mt < 4; ++mt){
    const int k0 = mt*16 + q*4;
    const int off = (((k0 >> 3) ^ rs) << 3) + (k0 & 7);
    _Float16* pA = zioA + lm*64 + off;
    _Float16* pB = zioB + lm*64 + off;
    v4h zA = *(const v4h*)pA;
    v4h zB = *(const v4h*)pB;
    float sA0 = accA[mt][0] * sreluD_from_z((float)zA[0]);
    float sA1 = accA[mt][1] * sreluD_from_z((float)zA[1]);
    float sA2 = accA[mt][2] * sreluD_from_z((float)zA[2]);
    float sA3 = accA[mt][3] * sreluD_from_z((float)zA[3]);
    float sB0 = accB[mt][0] * sreluD_from_z((float)zB[0]);
    float sB1 = accB[mt][1] * sreluD_from_z((float)zB[1]);
    float sB2 = accB[mt][2] * sreluD_from_z((float)zB[2]);
    float sB3 = accB[mt][3] * sreluD_from_z((float)zB[3]);
    v4h gA, gB;
    *(v2h*)&gA       = cvt_pk(sA0, sA1);
    *((v2h*)&gA + 1) = cvt_pk(sA2, sA3);
    *(v2h*)&gB       = cvt_pk(sB0, sB1);
    *((v2h*)&gB + 1) = cvt_pk(sB2, sB3);
    *(v4h*)pA = gA;
    *(v4h*)pB = gB;
  }
}

// ================= monolithic kernel =================
__global__ __launch_bounds__(256, 4) void icnn_mono(
  const float* __restrict__ X, const float* __restrict__ Xst,
  const float* __restrict__ Vfx,
  const float* __restrict__ f1b, const float* __restrict__ f2b,
  const float* __restrict__ f3b, const float* __restrict__ f4b,
  const float* __restrict__ f5b, const float* __restrict__ ffb,
  float* __restrict__ out)
{
  __shared__ __align__(16) char smem[50176];   // 48K arenas(overlay H) + 1K FH
  _Float16* const H  = (_Float16*)smem;        // [128][128] f16 swz
  float*    const FH = (float*)(smem + 49152); // [128][2] wave-local

  const int t  = threadIdx.x;
  const int b  = blockIdx.x;
  const int w  = t >> 6;
  const int l  = t & 63;
  const int lm = l & 15;
  const int q  = l >> 4;

  // ================= fhat phase (128 rows) =================
  {
    const int r = t >> 1, hf = t & 1, rsw = r & 15;
    int g = b*128 + r; if (g > NPTS-1) g = NPTS-1;
    const float2 xv = *(const float2*)(X + g*2);
    v2h xh; xh.x = (_Float16)xv.x; xh.y = (_Float16)xv.y;
#pragma unroll
    for (int c8 = 0; c8 < 8; ++c8){
      const int c = hf*8 + c8;
      const v4f b0 = *(const v4f*)(f1b + c*8);
      const v4f b1 = *(const v4f*)(f1b + c*8 + 4);
      float vv[8];
#pragma unroll
      for (int j = 0; j < 8; ++j){
        const v2h wv = *(const v2h*)(g_w16 + OFF_F1W + (c*8 + j)*2);
        const float bb = (j < 4) ? b0[j] : b1[j-4];
        vv[j] = FDOT2(xh, wv, bb);
      }
      v8h hv;
#pragma unroll
      for (int j2 = 0; j2 < 4; ++j2)
        ((v2h*)&hv)[j2] = lrelu_pk(vv[2*j2], vv[2*j2+1]);
      *(v8h*)(H + r*128 + ((c ^ rsw) << 3)) = hv;
    }
  }
  __syncthreads();

  fh_layer(H, g_w16 + OFF_FW,         f2b, w, lm, q);
  fh_layer(H, g_w16 + OFF_FW + 16384, f3b, w, lm, q);
  fh_layer(H, g_w16 + OFF_FW + 32768, f4b, w, lm, q);
  fh_layer(H, g_w16 + OFF_FW + 49152, f5b, w, lm, q);

  // head -> FH (wave-local LDS; thread t handles row t>>1 of its own wave)
  {
    const int r = t >> 1, c = t & 1, rsw = r & 15;
    float s = ffb[c];
    const v8h* wf = (const v8h*)(g_w16 + OFF_FFW + c*128);
#pragma unroll
    for (int ck = 0; ck < 16; ++ck){
      v8h h = *(const v8h*)(H + r*128 + ((ck ^ rsw) << 3));
      s = dot8(h, wf[ck], s);
    }
    FH[r*2 + c] = s;
  }
  __syncthreads();   // H dead; arenas may overlay

  // ================= vnet phase (same 128 rows, wave-private ILP2) =================
  const int rs = lm & 7;
  _Float16* const ZA1 = (_Float16*)(smem + w*12288);   // 6 x 2 KB per wave
  _Float16* const ZA2 = ZA1 + 1024;
  _Float16* const ZA3 = ZA1 + 2048;
  _Float16* const ZB1 = ZA1 + 3072;
  _Float16* const ZB2 = ZA1 + 4096;
  _Float16* const ZB3 = ZA1 + 5120;

  const int rowA = b*128 + w*32 + lm;
  const int rowB = rowA + 16;
  const int rcA = rowA < NPTS ? rowA : NPTS-1;
  const int rcB = rowB < NPTS ? rowB : NPTS-1;
  const float2 xA = *(const float2*)(X   + rcA*2);
  const float2 sA = *(const float2*)(Xst + rcA*2);
  const float2 xB = *(const float2*)(X   + rcB*2);
  const float2 sB = *(const float2*)(Xst + rcB*2);
  const float dA0 = xA.x - sA.x, dA1 = xA.y - sA.y;
  const float dB0 = xB.x - sB.x, dB1 = xB.y - sB.y;
  const float vfx0 = Vfx[0], vfx1 = Vfx[1];

  // z1 for both pipelines (shared weight regs)
  {
    v8h w0a = *(const v8h*)(g_w16 + OFF_VL1T + q*16);
    v8h w0b = *(const v8h*)(g_w16 + OFF_VL1T + q*16 + 8);
    v8h w1a = *(const v8h*)(g_w16 + OFF_VL1T + 64 + q*16);
    v8h w1b = *(const v8h*)(g_w16 + OFF_VL1T + 64 + q*16 + 8);
    v8h zaA, zbA, zaB, zbB;
#pragma unroll
    for (int j2 = 0; j2 < 4; ++j2){
      float a0 = (float)w0a[2*j2  ], a1 = (float)w0a[2*j2+1];
      float b0 = (float)w0b[2*j2  ], b1 = (float)w0b[2*j2+1];
      float c0 = (float)w1a[2*j2  ], c1 = (float)w1a[2*j2+1];
      float e0 = (float)w1b[2*j2  ], e1 = (float)w1b[2*j2+1];
      ((v2h*)&zaA)[j2] = srelu_pk(fmaf(dA0,a0,dA1*c0), fmaf(dA0,a1,dA1*c1));
      ((v2h*)&zbA)[j2] = srelu_pk(fmaf(dA0,b0,dA1*e0), fmaf(dA0,b1,dA1*e1));
      ((v2h*)&zaB)[j2] = srelu_pk(fmaf(dB0,a0,dB1*c0), fmaf(dB0,a1,dB1*c1));
      ((v2h*)&zbB)[j2] = srelu_pk(fmaf(dB0,b0,dB1*e0), fmaf(dB0,b1,dB1*e1));
    }
    const int s0 = (((q*2    ) ^ rs) << 3);
    const int s1 = (((q*2 + 1) ^ rs) << 3);
    *(v8h*)(ZA1 + lm*64 + s0) = zaA;
    *(v8h*)(ZA1 + lm*64 + s1) = zbA;
    *(v8h*)(ZB1 + lm*64 + s0) = zaB;
    *(v8h*)(ZB1 + lm*64 + s1) = zbB;
  }

  vfwd2(ZA1, ZA2, ZB1, ZB2, g_w16 + OFF_V2Z, g_w16 + OFF_V2XT,
        dA0, dA1, dB0, dB1, lm, q);
  vfwd2(ZA2, ZA3, ZB2, ZB3, g_w16 + OFF_V3Z, g_w16 + OFF_V3XT,
        dA0, dA1, dB0, dB1, lm, q);

  // zf head for both (A row 0 = Vfz, shared)
  float VVrA, sfA, VVrB, sfB;
  {
    v4f aSA = (v4f){0.f,0.f,0.f,0.f};
    v4f aSB = (v4f){0.f,0.f,0.f,0.f};
#pragma unroll
    for (int kt = 0; kt < 2; ++kt){
      const int sw = (((kt*4 + q) ^ rs) << 3);
      v8h A  = *(const v8h*)(g_w16 + OFF_VFZ + lm*64 + kt*32 + q*8);
      v8h BA = *(const v8h*)(ZA3 + lm*64 + sw);
      v8h BB = *(const v8h*)(ZB3 + lm*64 + sw);
      aSA = __builtin_amdgcn_mfma_f32_16x16x32_f16(A, BA, aSA, 0,0,0);
      aSB = __builtin_amdgcn_mfma_f32_16x16x32_f16(A, BB, aSB, 0,0,0);
    }
    const float afA = fmaf(vfx0, dA0, fmaf(vfx1, dA1, aSA[0]));
    const float zfA = srelu(afA);
    VVrA = srelu(zfA) + 0.01f * fmaf(dA0, dA0, dA1*dA1);
    sfA  = sreluD(zfA) * sreluD(afA);
    const float afB = fmaf(vfx0, dB0, fmaf(vfx1, dB1, aSB[0]));
    const float zfB = srelu(afB);
    VVrB = srelu(zfB) + 0.01f * fmaf(dB0, dB0, dB1*dB1);
    sfB  = sreluD(zfB) * sreluD(afB);
  }

  // u3 = Vfz * srelu'(a3) for both (sf deferred)
#pragma unroll
  for (int cc = 0; cc < 2; ++cc){
    const int c = q*2 + cc;
    const int sw = ((c ^ rs) << 3);
    v8h vf = *(const v8h*)(g_w16 + OFF_VFZ + c*8);
    _Float16* pA = ZA3 + lm*64 + sw;
    _Float16* pB = ZB3 + lm*64 + sw;
    v8h zA = *(const v8h*)pA;
    v8h zB = *(const v8h*)pB;
    v8h uA, uB;
#pragma unroll
    for (int j2 = 0; j2 < 4; ++j2){
      float a0 = (float)vf[2*j2  ] * sreluD_from_z((float)zA[2*j2  ]);
      float a1 = (float)vf[2*j2+1] * sreluD_from_z((float)zA[2*j2+1]);
      float b0 = (float)vf[2*j2  ] * sreluD_from_z((float)zB[2*j2  ]);
      float b1 = (float)vf[2*j2+1] * sreluD_from_z((float)zB[2*j2+1]);
      ((v2h*)&uA)[j2] = cvt_pk(a0, a1);
      ((v2h*)&uB)[j2] = cvt_pk(b0, b1);
    }
    *(v8h*)pA = uA;
    *(v8h*)pB = uB;
  }

  vbwd2(ZA3, ZA2, ZB3, ZB2, g_w16 + OFF_V3ZT, lm, q);
  vbwd2(ZA2, ZA1, ZB2, ZB1, g_w16 + OFF_V2ZT, lm, q);

  // gradV for both (A rows 0/1 = Wx^T, shared); apply sf once
  float g0A, g1A, g0B, g1B;
  {
    v4f aGA = (v4f){0.f,0.f,0.f,0.f};
    v4f aGB = (v4f){0.f,0.f,0.f,0.f};
    const _Float16* ZsA[3] = {ZA1, ZA2, ZA3};
    const _Float16* ZsB[3] = {ZB1, ZB2, ZB3};
    const int       Ws[3]  = {OFF_VL1T, OFF_V2XT, OFF_V3XT};
#pragma unroll
    for (int li = 0; li < 3; ++li){
#pragma unroll
      for (int kt = 0; kt < 2; ++kt){
        const int sw = (((kt*4 + q) ^ rs) << 3);
        v8h A  = *(const v8h*)(g_w16 + Ws[li] + lm*64 + kt*32 + q*8);
        v8h BA = *(const v8h*)(ZsA[li] + lm*64 + sw);
        v8h BB = *(const v8h*)(ZsB[li] + lm*64 + sw);
        aGA = __builtin_amdgcn_mfma_f32_16x16x32_f16(A, BA, aGA, 0,0,0);
        aGB = __builtin_amdgcn_mfma_f32_16x16x32_f16(A, BB, aGB, 0,0,0);
      }
    }
    g0A = fmaf(0.02f, dA0, sfA * (vfx0 + aGA[0]));
    g1A = fmaf(0.02f, dA1, sfA * (vfx1 + aGA[1]));
    g0B = fmaf(0.02f, dB0, sfB * (vfx0 + aGB[0]));
    g1B = fmaf(0.02f, dB1, sfB * (vfx1 + aGB[1]));
  }

  // epilogue: q==0 lanes; fh from wave-local LDS; write d_out directly
  if (q == 0){
    const int rA = w*32 + lm;
    const float fhA0 = FH[rA*2], fhA1 = FH[rA*2 + 1];
    const float fhB0 = FH[(rA+16)*2], fhB1 = FH[(rA+16)*2 + 1];
    if (rowA < NPTS){
      const float Vn  = fmaf(g0A, g0A, g1A*g1A);
      const float num = fmaf(0.1f, VVrA, fmaf(fhA0, g0A, fhA1*g1A));
      const float fm  = fmaxf(num, 0.f) / (Vn + 1e-10f);
      float2 o;
      o.x = fmaf(-g0A, fm, fhA0);
      o.y = fmaf(-g1A, fm, fhA1);
      *(float2*)(out + rowA*2) = o;
    }
    if (rowB < NPTS){
      const float Vn  = fmaf(g0B, g0B, g1B*g1B);
      const float num = fmaf(0.1f, VVrB, fmaf(fhB0, g0B, fhB1*g1B));
      const float fm  = fmaxf(num, 0.f) / (Vn + 1e-10f);
      float2 o;
      o.x = fmaf(-g0B, fm, fhB0);
      o.y = fmaf(-g1B, fm, fhB1);
      *(float2*)(out + rowB*2) = o;
    }
  }
}

extern "C" void kernel_launch(void* const* d_in, const int* in_sizes, int n_in,
                              void* d_out, int out_size, void* d_ws, size_t ws_size,
                              hipStream_t stream)
{
  (void)d_ws; (void)ws_size; (void)n_in; (void)in_sizes; (void)out_size;
  const float* X   = (const float*)d_in[0];
  const float* Xst = (const float*)d_in[1];
  const float* Vl1 = (const float*)d_in[2];
  const float* V2x = (const float*)d_in[3];
  const float* V2z = (const float*)d_in[4];
  const float* V3x = (const float*)d_in[5];
  const float* V3z = (const float*)d_in[6];
  const float* Vfx = (const float*)d_in[7];
  const float* Vfz = (const float*)d_in[8];
  const float* f1w = (const float*)d_in[9];
  const float* f1b = (const float*)d_in[10];
  const float* f2w = (const float*)d_in[11];
  const float* f2b = (const float*)d_in[12];
  const float* f3w = (const float*)d_in[13];
  const float* f3b = (const float*)d_in[14];
  const float* f4w = (const float*)d_in[15];
  const float* f4b = (const float*)d_in[16];
  const float* f5w = (const float*)d_in[17];
  const float* f5b = (const float*)d_in[18];
  const float* ffw = (const float*)d_in[19];
  const float* ffb = (const float*)d_in[20];

  prep_kernel<<<(W16_TOTAL + 255)/256, 256, 0, stream>>>(
      f2w, f3w, f4w, f5w, V2z, V3z, Vl1, V2x, V3x, Vfz, ffw, f1w);
  icnn_mono<<<NBLK, 256, 0, stream>>>(
      X, Xst, Vfx, f1b, f2b, f3b, f4b, f5b, ffb, (float*)d_out);
}

// Round 18
// 307.058 us; speedup vs baseline: 1.4211x; 1.4211x over previous
//
#include <hip/hip_runtime.h>

// ICNN_net_1503238553972 — round 18: R16 (best, 354.6us) with vnet LDS
// 48->32 KB: (1) z1 built in registers for layer-2 B-frags (srelu(Vl1.d)
// per lane) and srelu'(a1) recomputed exactly in backward — Z1 arenas gone;
// (2) gradV accumulated incrementally (L3 before ga2 overwrite, ga1 reuses
// Z2 arena). Fused LDS = 32 KB -> 4-5 blocks/CU (vs 3), keeping ILP-2.
// fhat body + combine + prep unchanged from R16. launch_bounds(256,4).

typedef _Float16 v2h __attribute__((ext_vector_type(2)));
typedef __fp16   v2hf __attribute__((ext_vector_type(2)));
typedef _Float16 v4h __attribute__((ext_vector_type(4)));
typedef _Float16 v8h __attribute__((ext_vector_type(8)));
typedef float    v4f __attribute__((ext_vector_type(4)));

__device__ __forceinline__ v2h cvt_pk(float a, float b){
  v2hf r = __builtin_amdgcn_cvt_pkrtz(a, b);
  union { v2hf f; v2h h; } u; u.f = r;
  return u.h;
}

#define NPTS 500000
#define FH_BLK  ((NPTS + 127) / 128)   // 3907
#define VN_BLK  ((NPTS + 127) / 128)   // 3907 (128 rows/block)
#define FUSED_GRID (FH_BLK + VN_BLK)   // 7814

// offsets in halves inside g_w16
#define OFF_FW    0               // f2..f5: L*16384, [o*128+k]
#define OFF_V2Z   65536           // [j*64+k]
#define OFF_V3Z   69632
#define OFF_V2ZT  73728           // [k*64+j]
#define OFF_V3ZT  77824
#define OFF_VL1T  81920           // [c*64+j]
#define OFF_V2XT  82048
#define OFF_V3XT  82176
#define OFF_VFZ   82304           // [64]
#define OFF_FFW   82368           // [c*128+k]
#define OFF_F1W   82624           // [oc*2+c]
#define W16_DATA  82880
#define W16_TOTAL (W16_DATA + 2048)   // zero pad: junk A-rows stay in-bounds

__device__ __align__(16) _Float16 g_w16[W16_TOTAL];
__device__ __align__(16) float    g_fh[NPTS * 2];   // f_hat per row (fp32)
__device__ __align__(16) float4   g_grad[NPTS];     // (g0, g1, V, pad)

#if defined(__has_builtin)
#if __has_builtin(__builtin_amdgcn_fdot2)
#define FDOT2(a,b,c) __builtin_amdgcn_fdot2((a),(b),(c),false)
#endif
#endif
#ifndef FDOT2
__device__ __forceinline__ float fdot2_fb(v2h a, v2h b, float c){
  return fmaf((float)a.x, (float)b.x, fmaf((float)a.y, (float)b.y, c));
}
#define FDOT2(a,b,c) fdot2_fb((a),(b),(c))
#endif

__device__ __forceinline__ float srelu(float x){
  float c = fminf(fmaxf(x, 0.f), 1.f);
  return c * fmaf(-0.5f, c, x);
}
__device__ __forceinline__ float sreluD(float x){
  return fminf(fmaxf(x, 0.f), 1.f);
}
__device__ __forceinline__ float sreluD_from_z(float z){
  return fminf(sqrtf(2.f * z), 1.f);
}
__device__ __forceinline__ float dot8(v8h a, v8h b, float s){
  const v2h* ap = (const v2h*)&a;
  const v2h* bp = (const v2h*)&b;
  s = FDOT2(ap[0], bp[0], s);
  s = FDOT2(ap[1], bp[1], s);
  s = FDOT2(ap[2], bp[2], s);
  s = FDOT2(ap[3], bp[3], s);
  return s;
}

// ---- packed f16 activations (2 f32 in -> 2 f16 out) ----
__device__ __forceinline__ v2h lrelu_pk(float a, float b){
  v2h x = cvt_pk(a, b);
  v2h m = x * (v2h){(_Float16)0.01f, (_Float16)0.01f};
  return __builtin_elementwise_max(x, m);
}
__device__ __forceinline__ v2h srelu_pk(float a, float b){
  v2h x = cvt_pk(a, b);
  const v2h z0 = (v2h){(_Float16)0.f, (_Float16)0.f};
  const v2h o1 = (v2h){(_Float16)1.f, (_Float16)1.f};
  const v2h hf = (v2h){(_Float16)0.5f, (_Float16)0.5f};
  v2h c = __builtin_elementwise_min(__builtin_elementwise_max(x, z0), o1);
  v2h t = x - c * hf;
  return c * t;
}

// ---------------- prep: fp32 weights -> f16 layouts (+zero pad) ----------------
__global__ __launch_bounds__(256) void prep_kernel(
  const float* __restrict__ f2w, const float* __restrict__ f3w,
  const float* __restrict__ f4w, const float* __restrict__ f5w,
  const float* __restrict__ V2z, const float* __restrict__ V3z,
  const float* __restrict__ Vl1, const float* __restrict__ V2x,
  const float* __restrict__ V3x, const float* __restrict__ Vfz,
  const float* __restrict__ ffw, const float* __restrict__ f1w)
{
  const int i = blockIdx.x * 256 + threadIdx.x;
  if (i >= W16_TOTAL) return;
  if (i >= W16_DATA){ g_w16[i] = (_Float16)0.f; return; }
  float v;
  if (i < 65536){
    const float* W[4] = {f2w, f3w, f4w, f5w};
    v = W[i >> 14][i & 16383];
  } else if (i < 69632)  v = V2z[i - 65536];
  else if (i < 73728)    v = V3z[i - 69632];
  else if (i < 77824){ int r = i - 73728; v = V2z[(r & 63)*64 + (r >> 6)]; }
  else if (i < 81920){ int r = i - 77824; v = V3z[(r & 63)*64 + (r >> 6)]; }
  else if (i < 82048){ int r = i - 81920; v = Vl1[(r & 63)*2 + (r >> 6)]; }
  else if (i < 82176){ int r = i - 82048; v = V2x[(r & 63)*2 + (r >> 6)]; }
  else if (i < 82304){ int r = i - 82176; v = V3x[(r & 63)*2 + (r >> 6)]; }
  else if (i < 82368)    v = Vfz[i - 82304];
  else if (i < 82624)    v = ffw[i - 82368];
  else                   v = f1w[i - 82624];
  g_w16[i] = (_Float16)v;
}

// ================= fhat block body: 256 thr, 128 rows =================
__device__ __forceinline__ void fh_layer(_Float16* H,
    const _Float16* __restrict__ Wl, const float* __restrict__ Bp,
    int w, int lm, int q)
{
  v4f acc[2][8];
#pragma unroll
  for (int mt = 0; mt < 2; ++mt)
#pragma unroll
    for (int nt = 0; nt < 8; ++nt) acc[mt][nt] = (v4f){0.f,0.f,0.f,0.f};

#pragma unroll
  for (int kt = 0; kt < 4; ++kt){
    const int sw = ((kt*4 + q) ^ lm) << 3;
    v8h A0 = *(const v8h*)(Wl + (w*32      + lm)*128 + kt*32 + q*8);
    v8h A1 = *(const v8h*)(Wl + (w*32 + 16 + lm)*128 + kt*32 + q*8);
#pragma unroll
    for (int nt = 0; nt < 8; ++nt){
      v8h B = *(const v8h*)(H + (nt*16 + lm)*128 + sw);
      acc[0][nt] = __builtin_amdgcn_mfma_f32_16x16x32_f16(A0, B, acc[0][nt], 0,0,0);
      acc[1][nt] = __builtin_amdgcn_mfma_f32_16x16x32_f16(A1, B, acc[1][nt], 0,0,0);
    }
  }
  __syncthreads();
#pragma unroll
  for (int mt = 0; mt < 2; ++mt){
    const int o0 = w*32 + mt*16 + q*4;
    const v4f bv = *(const v4f*)(Bp + o0);
    const int coff = (((o0 >> 3) ^ lm) << 3) + (o0 & 7);
#pragma unroll
    for (int nt = 0; nt < 8; ++nt){
      v4h hv;
      *(v2h*)&hv       = lrelu_pk(acc[mt][nt][0] + bv[0], acc[mt][nt][1] + bv[1]);
      *((v2h*)&hv + 1) = lrelu_pk(acc[mt][nt][2] + bv[2], acc[mt][nt][3] + bv[3]);
      *(v4h*)(H + (nt*16 + lm)*128 + coff) = hv;
    }
  }
  __syncthreads();
}

__device__ __forceinline__ void fhat_body(int b, _Float16* H,
  const float* __restrict__ X,
  const float* __restrict__ f1b, const float* __restrict__ f2b,
  const float* __restrict__ f3b, const float* __restrict__ f4b,
  const float* __restrict__ f5b, const float* __restrict__ ffb)
{
  const int t  = threadIdx.x;
  const int w  = t >> 6;
  const int l  = t & 63;
  const int lm = l & 15;
  const int q  = l >> 4;

  {
    const int r = t >> 1, hf = t & 1, rsw = r & 15;
    int g = b*128 + r; if (g > NPTS-1) g = NPTS-1;
    const float2 xv = *(const float2*)(X + g*2);
    v2h xh; xh.x = (_Float16)xv.x; xh.y = (_Float16)xv.y;
#pragma unroll
    for (int c8 = 0; c8 < 8; ++c8){
      const int c = hf*8 + c8;
      const v4f b0 = *(const v4f*)(f1b + c*8);
      const v4f b1 = *(const v4f*)(f1b + c*8 + 4);
      float vv[8];
#pragma unroll
      for (int j = 0; j < 8; ++j){
        const v2h wv = *(const v2h*)(g_w16 + OFF_F1W + (c*8 + j)*2);
        const float bb = (j < 4) ? b0[j] : b1[j-4];
        vv[j] = FDOT2(xh, wv, bb);
      }
      v8h hv;
#pragma unroll
      for (int j2 = 0; j2 < 4; ++j2)
        ((v2h*)&hv)[j2] = lrelu_pk(vv[2*j2], vv[2*j2+1]);
      *(v8h*)(H + r*128 + ((c ^ rsw) << 3)) = hv;
    }
  }
  __syncthreads();

  fh_layer(H, g_w16 + OFF_FW,         f2b, w, lm, q);
  fh_layer(H, g_w16 + OFF_FW + 16384, f3b, w, lm, q);
  fh_layer(H, g_w16 + OFF_FW + 32768, f4b, w, lm, q);
  fh_layer(H, g_w16 + OFF_FW + 49152, f5b, w, lm, q);

  {
    const int r = t >> 1, c = t & 1, rsw = r & 15;
    float s = ffb[c];
    const v8h* wf = (const v8h*)(g_w16 + OFF_FFW + c*128);
#pragma unroll
    for (int ck = 0; ck < 16; ++ck){
      v8h h = *(const v8h*)(H + r*128 + ((ck ^ rsw) << 3));
      s = dot8(h, wf[ck], s);
    }
    const int row = b*128 + r;
    if (row < NPTS) g_fh[row*2 + c] = s;
  }
}

// ================= vnet: ILP-2, 2 arenas/pipeline =================
// layer-2 fwd: z1 B-fragments built in REGISTERS (no Z1 arena).
__device__ __forceinline__ void vfwd2_l2(_Float16* zoutA, _Float16* zoutB,
    const _Float16* __restrict__ Wz,   // V2Z [o][k]
    const _Float16* __restrict__ WxT,  // V2XT [2][64]
    const _Float16* __restrict__ Wl1T, // VL1T [2][64]
    float dA0, float dA1, float dB0, float dB1, int lm, int q)
{
  v4f accA[4], accB[4];
#pragma unroll
  for (int mt = 0; mt < 4; ++mt){
    accA[mt] = (v4f){0.f,0.f,0.f,0.f};
    accB[mt] = (v4f){0.f,0.f,0.f,0.f};
  }
  const int rs = lm & 7;
#pragma unroll
  for (int kt = 0; kt < 2; ++kt){
    v8h w0 = *(const v8h*)(Wl1T + kt*32 + q*8);
    v8h w1 = *(const v8h*)(Wl1T + 64 + kt*32 + q*8);
    v8h BA, BB;
#pragma unroll
    for (int j2 = 0; j2 < 4; ++j2){
      const float a0 = (float)w0[2*j2  ], a1 = (float)w0[2*j2+1];
      const float c0 = (float)w1[2*j2  ], c1 = (float)w1[2*j2+1];
      ((v2h*)&BA)[j2] = srelu_pk(fmaf(dA0,a0,dA1*c0), fmaf(dA0,a1,dA1*c1));
      ((v2h*)&BB)[j2] = srelu_pk(fmaf(dB0,a0,dB1*c0), fmaf(dB0,a1,dB1*c1));
    }
#pragma unroll
    for (int mt = 0; mt < 4; ++mt){
      v8h A = *(const v8h*)(Wz + (mt*16 + lm)*64 + kt*32 + q*8);
      accA[mt] = __builtin_amdgcn_mfma_f32_16x16x32_f16(A, BA, accA[mt], 0,0,0);
      accB[mt] = __builtin_amdgcn_mfma_f32_16x16x32_f16(A, BB, accB[mt], 0,0,0);
    }
  }
#pragma unroll
  for (int mt = 0; mt < 4; ++mt){
    const int o0 = mt*16 + q*4;
    const int off = (((o0 >> 3) ^ rs) << 3) + (o0 & 7);
    float vA[4], vB[4];
#pragma unroll
    for (int reg = 0; reg < 4; ++reg){
      const float wx0 = (float)WxT[o0 + reg];
      const float wx1 = (float)WxT[64 + o0 + reg];
      vA[reg] = accA[mt][reg] + wx0*dA0 + wx1*dA1;
      vB[reg] = accB[mt][reg] + wx0*dB0 + wx1*dB1;
    }
    v4h hA, hB;
    *(v2h*)&hA       = srelu_pk(vA[0], vA[1]);
    *((v2h*)&hA + 1) = srelu_pk(vA[2], vA[3]);
    *(v2h*)&hB       = srelu_pk(vB[0], vB[1]);
    *((v2h*)&hB + 1) = srelu_pk(vB[2], vB[3]);
    *(v4h*)(zoutA + lm*64 + off) = hA;
    *(v4h*)(zoutB + lm*64 + off) = hB;
  }
}

// layer-3 fwd (B from LDS) — unchanged from R16
__device__ __forceinline__ void vfwd2(const _Float16* zinA, _Float16* zoutA,
    const _Float16* zinB, _Float16* zoutB,
    const _Float16* __restrict__ Wz, const _Float16* __restrict__ WxT,
    float dA0, float dA1, float dB0, float dB1, int lm, int q)
{
  v4f accA[4], accB[4];
#pragma unroll
  for (int mt = 0; mt < 4; ++mt){
    accA[mt] = (v4f){0.f,0.f,0.f,0.f};
    accB[mt] = (v4f){0.f,0.f,0.f,0.f};
  }
  const int rs = lm & 7;
#pragma unroll
  for (int kt = 0; kt < 2; ++kt){
    const int sw = (((kt*4 + q) ^ rs) << 3);
    v8h BA = *(const v8h*)(zinA + lm*64 + sw);
    v8h BB = *(const v8h*)(zinB + lm*64 + sw);
#pragma unroll
    for (int mt = 0; mt < 4; ++mt){
      v8h A = *(const v8h*)(Wz + (mt*16 + lm)*64 + kt*32 + q*8);
      accA[mt] = __builtin_amdgcn_mfma_f32_16x16x32_f16(A, BA, accA[mt], 0,0,0);
      accB[mt] = __builtin_amdgcn_mfma_f32_16x16x32_f16(A, BB, accB[mt], 0,0,0);
    }
  }
#pragma unroll
  for (int mt = 0; mt < 4; ++mt){
    const int o0 = mt*16 + q*4;
    const int off = (((o0 >> 3) ^ rs) << 3) + (o0 & 7);
    float vA[4], vB[4];
#pragma unroll
    for (int reg = 0; reg < 4; ++reg){
      const float wx0 = (float)WxT[o0 + reg];
      const float wx1 = (float)WxT[64 + o0 + reg];
      vA[reg] = accA[mt][reg] + wx0*dA0 + wx1*dA1;
      vB[reg] = accB[mt][reg] + wx0*dB0 + wx1*dB1;
    }
    v4h hA, hB;
    *(v2h*)&hA       = srelu_pk(vA[0], vA[1]);
    *((v2h*)&hA + 1) = srelu_pk(vA[2], vA[3]);
    *(v2h*)&hB       = srelu_pk(vB[0], vB[1]);
    *((v2h*)&hB + 1) = srelu_pk(vB[2], vB[3]);
    *(v4h*)(zoutA + lm*64 + off) = hA;
    *(v4h*)(zoutB + lm*64 + off) = hB;
  }
}

// backward layer-3->2 (srelu' from stored z, in place) — unchanged from R16
__device__ __forceinline__ void vbwd2(const _Float16* ginA, _Float16* zioA,
    const _Float16* ginB, _Float16* zioB,
    const _Float16* __restrict__ WT, int lm, int q)
{
  v4f accA[4], accB[4];
#pragma unroll
  for (int mt = 0; mt < 4; ++mt){
    accA[mt] = (v4f){0.f,0.f,0.f,0.f};
    accB[mt] = (v4f){0.f,0.f,0.f,0.f};
  }
  const int rs = lm & 7;
#pragma unroll
  for (int kt = 0; kt < 2; ++kt){
    const int sw = (((kt*4 + q) ^ rs) << 3);
    v8h BA = *(const v8h*)(ginA + lm*64 + sw);
    v8h BB = *(const v8h*)(ginB + lm*64 + sw);
#pragma unroll
    for (int mt = 0; mt < 4; ++mt){
      v8h A = *(const v8h*)(WT + (mt*16 + lm)*64 + kt*32 + q*8);
      accA[mt] = __builtin_amdgcn_mfma_f32_16x16x32_f16(A, BA, accA[mt], 0,0,0);
      accB[mt] = __builtin_amdgcn_mfma_f32_16x16x32_f16(A, BB, accB[mt], 0,0,0);
    }
  }
#pragma unroll
  for (int mt = 0; mt < 4; ++mt){
    const int k0 = mt*16 + q*4;
    const int off = (((k0 >> 3) ^ rs) << 3) + (k0 & 7);
    _Float16* pA = zioA + lm*64 + off;
    _Float16* pB = zioB + lm*64 + off;
    v4h zA = *(const v4h*)pA;
    v4h zB = *(const v4h*)pB;
    float sA0 = accA[mt][0] * sreluD_from_z((float)zA[0]);
    float sA1 = accA[mt][1] * sreluD_from_z((float)zA[1]);
    float sA2 = accA[mt][2] * sreluD_from_z((float)zA[2]);
    float sA3 = accA[mt][3] * sreluD_from_z((float)zA[3]);
    float sB0 = accB[mt][0] * sreluD_from_z((float)zB[0]);
    float sB1 = accB[mt][1] * sreluD_from_z((float)zB[1]);
    float sB2 = accB[mt][2] * sreluD_from_z((float)zB[2]);
    float sB3 = accB[mt][3] * sreluD_from_z((float)zB[3]);
    v4h gA, gB;
    *(v2h*)&gA       = cvt_pk(sA0, sA1);
    *((v2h*)&gA + 1) = cvt_pk(sA2, sA3);
    *(v2h*)&gB       = cvt_pk(sB0, sB1);
    *((v2h*)&gB + 1) = cvt_pk(sB2, sB3);
    *(v4h*)pA = gA;
    *(v4h*)pB = gB;
  }
}

// backward layer-2->1: srelu'(a1) recomputed exactly; ga1 reuses the Z2 arena.
__device__ __forceinline__ void vbwd2_l1(_Float16* zioA, _Float16* zioB,
    const _Float16* __restrict__ WT,   // V2ZT
    const _Float16* __restrict__ Wl1T, // VL1T [2][64]
    float dA0, float dA1, float dB0, float dB1, int lm, int q)
{
  v4f accA[4], accB[4];
#pragma unroll
  for (int mt = 0; mt < 4; ++mt){
    accA[mt] = (v4f){0.f,0.f,0.f,0.f};
    accB[mt] = (v4f){0.f,0.f,0.f,0.f};
  }
  const int rs = lm & 7;
#pragma unroll
  for (int kt = 0; kt < 2; ++kt){
    const int sw = (((kt*4 + q) ^ rs) << 3);
    v8h BA = *(const v8h*)(zioA + lm*64 + sw);
    v8h BB = *(const v8h*)(zioB + lm*64 + sw);
#pragma unroll
    for (int mt = 0; mt < 4; ++mt){
      v8h A = *(const v8h*)(WT + (mt*16 + lm)*64 + kt*32 + q*8);
      accA[mt] = __builtin_amdgcn_mfma_f32_16x16x32_f16(A, BA, accA[mt], 0,0,0);
      accB[mt] = __builtin_amdgcn_mfma_f32_16x16x32_f16(A, BB, accB[mt], 0,0,0);
    }
  }
#pragma unroll
  for (int mt = 0; mt < 4; ++mt){
    const int k0 = mt*16 + q*4;
    const int off = (((k0 >> 3) ^ rs) << 3) + (k0 & 7);
    v4h w0 = *(const v4h*)(Wl1T + k0);
    v4h w1 = *(const v4h*)(Wl1T + 64 + k0);
    float sA[4], sB[4];
#pragma unroll
    for (int reg = 0; reg < 4; ++reg){
      const float a1A = fmaf(dA0, (float)w0[reg], dA1 * (float)w1[reg]);
      const float a1B = fmaf(dB0, (float)w0[reg], dB1 * (float)w1[reg]);
      sA[reg] = accA[mt][reg] * sreluD(a1A);
      sB[reg] = accB[mt][reg] * sreluD(a1B);
    }
    v4h gA, gB;
    *(v2h*)&gA       = cvt_pk(sA[0], sA[1]);
    *((v2h*)&gA + 1) = cvt_pk(sA[2], sA[3]);
    *(v2h*)&gB       = cvt_pk(sB[0], sB[1]);
    *((v2h*)&gB + 1) = cvt_pk(sB[2], sB[3]);
    *(v4h*)(zioA + lm*64 + off) = gA;
    *(v4h*)(zioB + lm*64 + off) = gB;
  }
}

// incremental gradV contribution: aG += WxT-rows MFMA over one arena pair
__device__ __forceinline__ void gacc2(v4f& aGA, v4f& aGB,
    const _Float16* __restrict__ WxTbase,
    const _Float16* ZA, const _Float16* ZB, int lm, int q)
{
  const int rs = lm & 7;
#pragma unroll
  for (int kt = 0; kt < 2; ++kt){
    const int sw = (((kt*4 + q) ^ rs) << 3);
    v8h A  = *(const v8h*)(WxTbase + lm*64 + kt*32 + q*8);
    v8h BA = *(const v8h*)(ZA + lm*64 + sw);
    v8h BB = *(const v8h*)(ZB + lm*64 + sw);
    aGA = __builtin_amdgcn_mfma_f32_16x16x32_f16(A, BA, aGA, 0,0,0);
    aGB = __builtin_amdgcn_mfma_f32_16x16x32_f16(A, BB, aGB, 0,0,0);
  }
}

__device__ __forceinline__ void vnet_body2(int b, char* smem,
  const float* __restrict__ X, const float* __restrict__ Xst,
  const float* __restrict__ Vfx)
{
  const int t  = threadIdx.x;
  const int w  = t >> 6;
  const int l  = t & 63;
  const int lm = l & 15;
  const int q  = l >> 4;
  const int rs = lm & 7;

  _Float16* const ZA2 = (_Float16*)(smem + w*8192);   // 4 x 2 KB per wave
  _Float16* const ZA3 = ZA2 + 1024;
  _Float16* const ZB2 = ZA2 + 2048;
  _Float16* const ZB3 = ZA2 + 3072;

  const int rowA = b*128 + w*32 + lm;
  const int rowB = rowA + 16;
  const int rcA = rowA < NPTS ? rowA : NPTS-1;
  const int rcB = rowB < NPTS ? rowB : NPTS-1;
  const float2 xA = *(const float2*)(X   + rcA*2);
  const float2 sA = *(const float2*)(Xst + rcA*2);
  const float2 xB = *(const float2*)(X   + rcB*2);
  const float2 sB = *(const float2*)(Xst + rcB*2);
  const float dA0 = xA.x - sA.x, dA1 = xA.y - sA.y;
  const float dB0 = xB.x - sB.x, dB1 = xB.y - sB.y;
  const float vfx0 = Vfx[0], vfx1 = Vfx[1];

  // fwd: z2 (z1 in registers), z3
  vfwd2_l2(ZA2, ZB2, g_w16 + OFF_V2Z, g_w16 + OFF_V2XT, g_w16 + OFF_VL1T,
           dA0, dA1, dB0, dB1, lm, q);
  vfwd2(ZA2, ZA3, ZB2, ZB3, g_w16 + OFF_V3Z, g_w16 + OFF_V3XT,
        dA0, dA1, dB0, dB1, lm, q);

  // zf head for both (A row 0 = Vfz)
  float VVrA, sfA, VVrB, sfB;
  {
    v4f aSA = (v4f){0.f,0.f,0.f,0.f};
    v4f aSB = (v4f){0.f,0.f,0.f,0.f};
#pragma unroll
    for (int kt = 0; kt < 2; ++kt){
      const int sw = (((kt*4 + q) ^ rs) << 3);
      v8h A  = *(const v8h*)(g_w16 + OFF_VFZ + lm*64 + kt*32 + q*8);
      v8h BA = *(const v8h*)(ZA3 + lm*64 + sw);
      v8h BB = *(const v8h*)(ZB3 + lm*64 + sw);
      aSA = __builtin_amdgcn_mfma_f32_16x16x32_f16(A, BA, aSA, 0,0,0);
      aSB = __builtin_amdgcn_mfma_f32_16x16x32_f16(A, BB, aSB, 0,0,0);
    }
    const float afA = fmaf(vfx0, dA0, fmaf(vfx1, dA1, aSA[0]));
    const float zfA = srelu(afA);
    VVrA = srelu(zfA) + 0.01f * fmaf(dA0, dA0, dA1*dA1);
    sfA  = sreluD(zfA) * sreluD(afA);
    const float afB = fmaf(vfx0, dB0, fmaf(vfx1, dB1, aSB[0]));
    const float zfB = srelu(afB);
    VVrB = srelu(zfB) + 0.01f * fmaf(dB0, dB0, dB1*dB1);
    sfB  = sreluD(zfB) * sreluD(afB);
  }

  // u3 = Vfz * srelu'(a3) (sf deferred; in place over Z3)
#pragma unroll
  for (int cc = 0; cc < 2; ++cc){
    const int c = q*2 + cc;
    const int sw = ((c ^ rs) << 3);
    v8h vf = *(const v8h*)(g_w16 + OFF_VFZ + c*8);
    _Float16* pA = ZA3 + lm*64 + sw;
    _Float16* pB = ZB3 + lm*64 + sw;
    v8h zA = *(const v8h*)pA;
    v8h zB = *(const v8h*)pB;
    v8h uA, uB;
#pragma unroll
    for (int j2 = 0; j2 < 4; ++j2){
      float a0 = (float)vf[2*j2  ] * sreluD_from_z((float)zA[2*j2  ]);
      float a1 = (float)vf[2*j2+1] * sreluD_from_z((float)zA[2*j2+1]);
      float b0 = (float)vf[2*j2  ] * sreluD_from_z((float)zB[2*j2  ]);
      float b1 = (float)vf[2*j2+1] * sreluD_from_z((float)zB[2*j2+1]);
      ((v2h*)&uA)[j2] = cvt_pk(a0, a1);
      ((v2h*)&uB)[j2] = cvt_pk(b0, b1);
    }
    *(v8h*)pA = uA;
    *(v8h*)pB = uB;
  }

  // incremental gradV, interleaved with backward (arena reuse)
  v4f aGA = (v4f){0.f,0.f,0.f,0.f};
  v4f aGB = (v4f){0.f,0.f,0.f,0.f};

  gacc2(aGA, aGB, g_w16 + OFF_V3XT, ZA3, ZB3, lm, q);             // L3 (ga3=u3)
  vbwd2(ZA3, ZA2, ZB3, ZB2, g_w16 + OFF_V3ZT, lm, q);             // ga2 -> Z2
  gacc2(aGA, aGB, g_w16 + OFF_V2XT, ZA2, ZB2, lm, q);             // L2
  vbwd2_l1(ZA2, ZB2, g_w16 + OFF_V2ZT, g_w16 + OFF_VL1T,
           dA0, dA1, dB0, dB1, lm, q);                            // ga1 -> Z2
  gacc2(aGA, aGB, g_w16 + OFF_VL1T, ZA2, ZB2, lm, q);             // L1

  const float g0A = fmaf(0.02f, dA0, sfA * (vfx0 + aGA[0]));
  const float g1A = fmaf(0.02f, dA1, sfA * (vfx1 + aGA[1]));
  const float g0B = fmaf(0.02f, dB0, sfB * (vfx0 + aGB[0]));
  const float g1B = fmaf(0.02f, dB1, sfB * (vfx1 + aGB[1]));

  if (q == 0){
    if (rowA < NPTS) g_grad[rowA] = make_float4(g0A, g1A, VVrA, 0.f);
    if (rowB < NPTS) g_grad[rowB] = make_float4(g0B, g1B, VVrB, 0.f);
  }
}

// ================= fused heterogeneous kernel =================
__global__ __launch_bounds__(256, 4) void fused_kernel(
  const float* __restrict__ X, const float* __restrict__ Xst,
  const float* __restrict__ Vfx,
  const float* __restrict__ f1b, const float* __restrict__ f2b,
  const float* __restrict__ f3b, const float* __restrict__ f4b,
  const float* __restrict__ f5b, const float* __restrict__ ffb)
{
  __shared__ __align__(16) char smem[32768];   // fhat 32 KB | vnet 32 KB
  const int g = blockIdx.x;
  if ((g & 1) == 0){
    fhat_body(g >> 1, (_Float16*)smem, X, f1b, f2b, f3b, f4b, f5b, ffb);
  } else {
    vnet_body2(g >> 1, smem, X, Xst, Vfx);
  }
}

// ================= combine epilogue (2 rows/thread, ~16 MB) =================
__global__ __launch_bounds__(256) void combine_kernel(float* __restrict__ out)
{
  const int idx = blockIdx.x * 256 + threadIdx.x;
  const int i0 = idx * 2;
  if (i0 >= NPTS) return;
  const float4 fh2 = *(const float4*)(g_fh + i0*2);
  const float4 ga = g_grad[i0];
  const float4 gb = g_grad[i0 + 1];
  float4 o;
  {
    const float Vn  = fmaf(ga.x, ga.x, ga.y*ga.y);
    const float num = fmaf(0.1f, ga.z, fmaf(fh2.x, ga.x, fh2.y*ga.y));
    const float fm  = fmaxf(num, 0.f) / (Vn + 1e-10f);
    o.x = fmaf(-ga.x, fm, fh2.x);
    o.y = fmaf(-ga.y, fm, fh2.y);
  }
  {
    const float Vn  = fmaf(gb.x, gb.x, gb.y*gb.y);
    const float num = fmaf(0.1f, gb.z, fmaf(fh2.z, gb.x, fh2.w*gb.y));
    const float fm  = fmaxf(num, 0.f) / (Vn + 1e-10f);
    o.z = fmaf(-gb.x, fm, fh2.z);
    o.w = fmaf(-gb.y, fm, fh2.w);
  }
  *(float4*)(out + i0*2) = o;
}

extern "C" void kernel_launch(void* const* d_in, const int* in_sizes, int n_in,
                              void* d_out, int out_size, void* d_ws, size_t ws_size,
                              hipStream_t stream)
{
  (void)d_ws; (void)ws_size; (void)n_in; (void)in_sizes; (void)out_size;
  const float* X   = (const float*)d_in[0];
  const float* Xst = (const float*)d_in[1];
  const float* Vl1 = (const float*)d_in[2];
  const float* V2x = (const float*)d_in[3];
  const float* V2z = (const float*)d_in[4];
  const float* V3x = (const float*)d_in[5];
  const float* V3z = (const float*)d_in[6];
  const float* Vfx = (const float*)d_in[7];
  const float* Vfz = (const float*)d_in[8];
  const float* f1w = (const float*)d_in[9];
  const float* f1b = (const float*)d_in[10];
  const float* f2w = (const float*)d_in[11];
  const float* f2b = (const float*)d_in[12];
  const float* f3w = (const float*)d_in[13];
  const float* f3b = (const float*)d_in[14];
  const float* f4w = (const float*)d_in[15];
  const float* f4b = (const float*)d_in[16];
  const float* f5w = (const float*)d_in[17];
  const float* f5b = (const float*)d_in[18];
  const float* ffw = (const float*)d_in[19];
  const float* ffb = (const float*)d_in[20];

  prep_kernel<<<(W16_TOTAL + 255)/256, 256, 0, stream>>>(
      f2w, f3w, f4w, f5w, V2z, V3z, Vl1, V2x, V3x, Vfz, ffw, f1w);
  fused_kernel<<<FUSED_GRID, 256, 0, stream>>>(
      X, Xst, Vfx, f1b, f2b, f3b, f4b, f5b, ffb);
  combine_kernel<<<(NPTS/2 + 255)/256, 256, 0, stream>>>((float*)d_out);
}